// Round 9
// baseline (262.899 us; speedup 1.0000x reference)
//
#include <hip/hip_runtime.h>
#include <math.h>

// Problem constants
constexpr int Bsz  = 64;
constexpr int Tseq = 256;
constexpr int Cdim = 384;
constexpr int Hh   = 6;
constexpr int HSd  = 64;
constexpr int Mrows = Bsz * Tseq;        // 16384
constexpr int Cffn  = 4 * Cdim;          // 1536
constexpr int Nqkv  = 3 * Cdim;          // 1152

typedef __attribute__((ext_vector_type(8))) short short8;  // 8 bf16 = 4 VGPRs
typedef __attribute__((ext_vector_type(4))) float f32x4;

// fp32 -> bf16 round-to-nearest-even
__device__ __forceinline__ ushort f2bf(float x) {
  union { float f; uint u; } a; a.f = x;
  uint r = a.u + 0x7fffu + ((a.u >> 16) & 1u);
  return (ushort)(r >> 16);
}
__device__ __forceinline__ float bf2f(ushort u) {
  union { uint u; float f; } a; a.u = ((uint)u) << 16;
  return a.f;
}
// Pack 2 f32 -> 2 bf16 (RNE) in one instruction (T12 recipe, no builtin).
__device__ __forceinline__ uint pk_bf16(float lo, float hi) {
  uint r;
  asm("v_cvt_pk_bf16_f32 %0, %1, %2" : "=v"(r) : "v"(lo), "v"(hi));
  return r;
}

// Fast GELU (tanh form): ~3e-4 max error vs exact-erf, ~8 VALU ops vs ~25.
__device__ __forceinline__ float gelu_fast(float x) {
  float t = x * x;
  float u = x * fmaf(0.044715f, t, 1.0f);
  float e = fminf(1.5957691216f * u, 80.f);
  float z = __expf(e);
  return x * (z / (1.0f + z));
}

// ---------------------------------------------------------------------------
// Fused prep: weight transpose-casts + bias concat + LN2-fold precompute.
// Blocks 0..1727 = 32x32 transpose tiles; 1728..1732 bqkv concat;
// 1733..1738 = colsum over W1 for the LN2 fold:
//   s_n   = sum_c ln2_w[c]*W1[c,n]
//   c2b_n = sum_c ln2_b[c]*W1[c,n] + b1[n]
// (reads the ORIGINAL W1, so no ordering hazard vs the W1T transpose blocks.)
// W1T is written SCALED: W1'[c,n] = ln2_w[c]*W1[c,n] (k-axis row scale).
// pih(c) = (c & ~63) + (c&15)*4 + ((c>>4)&3) k-permutation applied to:
// Wproj k-axis (matches QKV EPI=3 store) and W2 k-axis (matches FFN1 EPI
// store). Per-64-block only (row-wide perm broke store coalescing, R5).
// ---------------------------------------------------------------------------
__global__ __launch_bounds__(256) void prep_kernel(
    const float* __restrict__ Wq, const float* __restrict__ Wk,
    const float* __restrict__ Wv, const float* __restrict__ Wproj,
    const float* __restrict__ W1, const float* __restrict__ W2,
    const float* __restrict__ bq, const float* __restrict__ bk,
    const float* __restrict__ bv,
    const float* __restrict__ ln2_w, const float* __restrict__ ln2_b,
    const float* __restrict__ b1,
    ushort* __restrict__ WqkvT, ushort* __restrict__ WprojT,
    ushort* __restrict__ W1T, ushort* __restrict__ W2T,
    float* __restrict__ bqkv, float* __restrict__ sCol,
    float* __restrict__ c2b) {
  const int bid = blockIdx.x;
  if (bid >= 1733) {  // colsum over W1 (6 blocks x 256 threads = 1536 cols)
    const int n = (bid - 1733) * 256 + threadIdx.x;
    float s1 = 0.f, s2 = 0.f;
    for (int r = 0; r < Cdim; ++r) {
      float v = W1[(size_t)r * Cffn + n];
      s1 = fmaf(ln2_w[r], v, s1);
      s2 = fmaf(ln2_b[r], v, s2);
    }
    sCol[n] = s1;
    c2b[n] = s2 + b1[n];
    return;
  }
  if (bid >= 1728) {  // bias concat
    int i = (bid - 1728) * 256 + threadIdx.x;
    if (i < Nqkv)
      bqkv[i] = (i < 384) ? bq[i] : (i < 768) ? bk[i - 384] : bv[i - 768];
    return;
  }
  const int tx = threadIdx.x & 31, ty = threadIdx.x >> 5;  // 32 x 8
  const float* src; ushort* dst; int R, S, r0, s0, perm = 0;
  bool w1s = false;
  if (bid < 432) {           // Wq/Wk/Wv: [6][384][64] each -> rows of WqkvT
    int which = bid / 144, rem = bid % 144;
    const float* W = (which == 0) ? Wq : (which == 1) ? Wk : Wv;
    int bz = rem / 24, t = rem % 24;
    R = 384; S = 64;
    src = W + (size_t)bz * R * S;
    dst = WqkvT + (size_t)which * 384 * 384 + (size_t)bz * R * S;
    r0 = (t >> 1) * 32; s0 = (t & 1) * 32;
  } else if (bid < 576) {    // Wproj 384x384 (k-axis pih per 64-block)
    int rem = bid - 432; R = 384; S = 384; src = Wproj; dst = WprojT;
    r0 = (rem / 12) * 32; s0 = (rem % 12) * 32; perm = 1;
  } else if (bid < 1152) {   // W1 384x1536 -> W1T scaled by ln2_w (LN2 fold)
    int rem = bid - 576; R = 384; S = 1536; src = W1; dst = W1T;
    r0 = (rem / 48) * 32; s0 = (rem % 48) * 32; w1s = true;
  } else {                   // W2 1536x384 (k-axis pih per 64-block)
    int rem = bid - 1152; R = 1536; S = 384; src = W2; dst = W2T;
    r0 = (rem / 12) * 32; s0 = (rem % 12) * 32; perm = 1;
  }
  __shared__ float t[32][33];
#pragma unroll
  for (int i = 0; i < 32; i += 8)
    t[ty + i][tx] = src[(size_t)(r0 + ty + i) * S + s0 + tx];
  __syncthreads();
  const int kk = r0 + tx;   // source-row (k) index of this thread's values
  int kp = kk;
  if (perm) kp = (kk & ~63) | (((kk & 15) << 2) | ((kk >> 4) & 3));
  const float sc = w1s ? ln2_w[kk] : 1.f;
#pragma unroll
  for (int i = 0; i < 32; i += 8)
    dst[(size_t)(s0 + ty + i) * R + kp] = f2bf(t[tx][ty + i] * sc);
}

// ---------------------------------------------------------------------------
// LayerNorm: one wave per row of 384; 4 rows per block. bf16 output.
// ---------------------------------------------------------------------------
template <typename T>
__global__ __launch_bounds__(256) void ln_kernel(
    const T* __restrict__ x, const float* __restrict__ w,
    const float* __restrict__ b, ushort* __restrict__ out, int nrows) {
  int row  = blockIdx.x * 4 + (threadIdx.x >> 6);
  int lane = threadIdx.x & 63;
  if (row >= nrows) return;
  const T* xr = x + (size_t)row * Cdim;
  float v[6];
  float s = 0.f;
#pragma unroll
  for (int i = 0; i < 6; ++i) {
    if constexpr (sizeof(T) == 2) v[i] = bf2f(xr[lane + 64 * i]);
    else                          v[i] = xr[lane + 64 * i];
    s += v[i];
  }
#pragma unroll
  for (int off = 32; off > 0; off >>= 1) s += __shfl_xor(s, off, 64);
  float mean = s * (1.f / Cdim);
  float sq = 0.f;
#pragma unroll
  for (int i = 0; i < 6; ++i) { float d = v[i] - mean; sq += d * d; }
#pragma unroll
  for (int off = 32; off > 0; off >>= 1) sq += __shfl_xor(sq, off, 64);
  float rstd = rsqrtf(sq * (1.f / Cdim) + 1e-5f);
  ushort* orow = out + (size_t)row * Cdim;
#pragma unroll
  for (int i = 0; i < 6; ++i) {
    int c = lane + 64 * i;
    orow[c] = f2bf((v[i] - mean) * rstd * w[c] + b[c]);
  }
}

// ---------------------------------------------------------------------------
// LN2 stats only (fold support): per row of bf16 x1, write {rstd, rstd*mean}.
// Replaces the full LN2 kernel (saves the 12.6 MB normalized-row write).
// ---------------------------------------------------------------------------
__global__ __launch_bounds__(256) void stats_kernel(
    const ushort* __restrict__ x, float2* __restrict__ st, int nrows) {
  int row  = blockIdx.x * 4 + (threadIdx.x >> 6);
  int lane = threadIdx.x & 63;
  if (row >= nrows) return;
  const ushort* xr = x + (size_t)row * Cdim;
  float v[6];
  float s = 0.f;
#pragma unroll
  for (int i = 0; i < 6; ++i) { v[i] = bf2f(xr[lane + 64 * i]); s += v[i]; }
#pragma unroll
  for (int off = 32; off > 0; off >>= 1) s += __shfl_xor(s, off, 64);
  float mean = s * (1.f / Cdim);
  float sq = 0.f;
#pragma unroll
  for (int i = 0; i < 6; ++i) { float d = v[i] - mean; sq += d * d; }
#pragma unroll
  for (int off = 32; off > 0; off >>= 1) sq += __shfl_xor(sq, off, 64);
  float rstd = rsqrtf(sq * (1.f / Cdim) + 1e-5f);
  if (lane == 0) st[row] = make_float2(rstd, rstd * mean);
}

// ---------------------------------------------------------------------------
// bf16 MFMA GEMM: C[M,N] = epi(A[M,K] @ Bt[N,K]^T + bias). 128xBN tile, BK=64
// (R8's BK=32 raised occupancy 17.7->24.5% with ZERO speedup and added 2.4M
// bank conflicts -> structure is issue/lockstep-bound, not occupancy-bound;
// reverted to the proven R7 loop). Dbuf LDS + counted-vmcnt pipeline:
//   stage(t+1 -> buf^1); vmcnt(LPT); barrier;   // tile t landed, t+1 in flight
//   ds_read+MFMA on buf; lgkmcnt(0); barrier.
// LDS [buf][row][64], XOR chunk swizzle slot=(c&7)^(row&7); readers use
// quad (half*4+g)^(lm&7) -> all 8 bank-quads, 2-way (free, m136).
// XCD swizzle requires gridDim.y==128.
// EPI: 1 = +bias+res(fp32) -> bf16 (proj -> x1)
//      3 = QKV flat [M][1152], per-head pih-permuted dims (cvt_pk packed)
//      4 = +bias+res(bf16) -> fp32 (FFN2 -> out)
//      5 = folded-LN2 FFN1: A=x1, Bt=W1T(ln2_w-scaled), bias=c2b, res=stats
//          (float2{rstd, rstd*mean}), C2=sCol; y = gelu(rstd*acc -
//          rstd*mean*s_n + c2b_n) -> per-64-block pih-permuted g
// ---------------------------------------------------------------------------
template <int EPI, int BN>
__global__ __launch_bounds__(256) void mfma_gemm(
    const ushort* __restrict__ A, const ushort* __restrict__ Bt,
    const float* __restrict__ bias, const void* __restrict__ res,
    void* __restrict__ Cout, void* __restrict__ C2, void* __restrict__ C3,
    int M, int N, int K) {
  constexpr int WC = BN / 2;    // wave col span
  constexpr int JN = WC / 16;   // col frags per wave (4 or 2)
  constexpr int NB = BN / 32;   // B staging chunks per thread (4 or 2)
  __shared__ ushort Als[2 * 128 * 64];
  __shared__ ushort Bls[2 * BN * 64];
  const int tid = threadIdx.x;

  // XCD-aware remap (requires gridDim.y == 128)
  const int lid = blockIdx.y * gridDim.x + blockIdx.x;
  const int xcd = lid & 7, idx = lid >> 3;
  const int by = xcd * 16 + (idx & 15);
  const int bx = idx >> 4;
  const int m0 = by * 128, n0 = bx * BN;

  const int lane = tid & 63;
  const int w    = tid >> 6;
  const int wr   = (w >> 1) * 64;
  const int wc   = (w & 1) * WC;
  const int lm   = lane & 15;
  const int g    = lane >> 4;
  const int rq   = g * 4;

  const int wub = (tid & ~63) * 8;  // wave-uniform ushort offset of lane 0

  f32x4 acc[4][JN] = {};

  // Stage one BK=64 tile into LDS buffer `bf`.
  auto stage = [&](int k0, int bf) {
    ushort* Ab = Als + bf * (128 * 64);
    ushort* Bb = Bls + bf * (BN * 64);
#pragma unroll
    for (int q = 0; q < 4; ++q) {    // A: 128 rows x 8 chunks = 1024
      const int ci = tid + q * 256;
      const int row = ci >> 3;
      const int kc = ((ci & 7) ^ (row & 7)) * 8;
      const ushort* gA = A + (size_t)(m0 + row) * K + k0 + kc;
      __builtin_amdgcn_global_load_lds(
          (const __attribute__((address_space(1))) uint*)gA,
          (__attribute__((address_space(3))) uint*)(Ab + wub + q * 2048),
          16, 0, 0);
    }
#pragma unroll
    for (int q = 0; q < NB; ++q) {   // B: BN rows x 8 chunks
      const int ci = tid + q * 256;
      const int row = ci >> 3;
      const int kc = ((ci & 7) ^ (row & 7)) * 8;
      const ushort* gB = Bt + (size_t)(n0 + row) * K + k0 + kc;
      __builtin_amdgcn_global_load_lds(
          (const __attribute__((address_space(1))) uint*)gB,
          (__attribute__((address_space(3))) uint*)(Bb + wub + q * 2048),
          16, 0, 0);
    }
  };

  const int nt = K >> 6;
  stage(0, 0);

  for (int t = 0; t < nt; ++t) {
    const int cur = t & 1;
    if (t + 1 < nt) {
      stage((t + 1) * 64, cur ^ 1);
      // Wait only tile t's loads; the newest LPT (tile t+1) stay in flight.
      if constexpr (NB == 4)
        asm volatile("s_waitcnt vmcnt(8)" ::: "memory");
      else
        asm volatile("s_waitcnt vmcnt(6)" ::: "memory");
    } else {
      asm volatile("s_waitcnt vmcnt(0)" ::: "memory");
    }
    __builtin_amdgcn_sched_barrier(0);
    __builtin_amdgcn_s_barrier();      // everyone's tile-t loads landed
    __builtin_amdgcn_sched_barrier(0);

    const ushort* Ab = Als + cur * (128 * 64);
    const ushort* Bb = Bls + cur * (BN * 64);
#pragma unroll
    for (int half = 0; half < 2; ++half) {
      const int sl = ((half << 2) | g) ^ (lm & 7);  // swizzled chunk slot
      short8 af[4], bfr[JN];
#pragma unroll
      for (int i = 0; i < 4; ++i)
        af[i] = *(const short8*)&Ab[(wr + i * 16 + lm) * 64 + sl * 8];
#pragma unroll
      for (int j = 0; j < JN; ++j)
        bfr[j] = *(const short8*)&Bb[(wc + j * 16 + lm) * 64 + sl * 8];
      __builtin_amdgcn_s_setprio(1);
#pragma unroll
      for (int i = 0; i < 4; ++i)
#pragma unroll
        for (int j = 0; j < JN; ++j)
          acc[i][j] = __builtin_amdgcn_mfma_f32_16x16x32_bf16(af[i], bfr[j],
                                                              acc[i][j], 0, 0, 0);
      __builtin_amdgcn_s_setprio(0);
    }

    // All ds_reads retired; fence then barrier so next stage may overwrite.
    asm volatile("s_waitcnt lgkmcnt(0)" ::: "memory");
    __builtin_amdgcn_sched_barrier(0);
    __builtin_amdgcn_s_barrier();
    __builtin_amdgcn_sched_barrier(0);
  }

  float bb[JN];
#pragma unroll
  for (int j = 0; j < JN; ++j) bb[j] = bias[n0 + wc + j * 16 + lm];
  float sj[JN] = {};
  if constexpr (EPI == 5) {
#pragma unroll
    for (int j = 0; j < JN; ++j)
      sj[j] = ((const float*)C2)[n0 + wc + j * 16 + lm];
  }

#pragma unroll
  for (int i = 0; i < 4; ++i) {
#pragma unroll
    for (int r = 0; r < 4; ++r) {
      const int row = m0 + wr + i * 16 + rq + r;
      if constexpr (EPI == 1) {        // + fp32 residual -> bf16 out (true layout)
        const float* resrow = (const float*)res + (size_t)row * N + n0 + wc;
        ushort* crow = (ushort*)Cout + (size_t)row * N + n0 + wc;
#pragma unroll
        for (int j = 0; j < JN; ++j) {
          float rv = __builtin_nontemporal_load(resrow + j * 16 + lm);
          crow[j * 16 + lm] = f2bf(acc[i][j][r] + bb[j] + rv);
        }
      } else if constexpr (EPI == 4) { // + bf16 residual -> fp32 out
        const ushort* resrow = (const ushort*)res + (size_t)row * N + n0 + wc;
        float* crow = (float*)Cout + (size_t)row * N + n0 + wc;
#pragma unroll
        for (int j = 0; j < JN; ++j)
          crow[j * 16 + lm] = acc[i][j][r] + bb[j] + bf2f(resrow[j * 16 + lm]);
      } else if constexpr (EPI == 3) { // QKV flat, per-head pih perm (JN==4)
        // true col c = n0+wc+j*16+lm; stored at (n0+wc) + lm*4 + j.
        ushort* crow = (ushort*)Cout + (size_t)row * N + n0 + wc + lm * 4;
        uint d0 = pk_bf16(acc[i][0][r] + bb[0], acc[i][1][r] + bb[1]);
        uint d1 = pk_bf16(acc[i][2][r] + bb[2], acc[i][3][r] + bb[3]);
        uint2 pkv; pkv.x = d0; pkv.y = d1;
        *(uint2*)crow = pkv;
      } else {                         // EPI == 5: folded-LN2 gelu -> pih g
        const float2 st = ((const float2*)res)[row];  // {rstd, rstd*mean}
        ushort* crow = (ushort*)Cout + (size_t)row * N + n0 + wc + lm * 4;
        float v0 = fmaf(st.x, acc[i][0][r], fmaf(-st.y, sj[0], bb[0]));
        float v1 = fmaf(st.x, acc[i][1][r], fmaf(-st.y, sj[1], bb[1]));
        float v2 = fmaf(st.x, acc[i][2][r], fmaf(-st.y, sj[2], bb[2]));
        float v3 = fmaf(st.x, acc[i][3][r], fmaf(-st.y, sj[3], bb[3]));
        uint d0 = pk_bf16(gelu_fast(v0), gelu_fast(v1));
        uint d1 = pk_bf16(gelu_fast(v2), gelu_fast(v3));
        uint2 pkv; pkv.x = d0; pkv.y = d1;
        *(uint2*)crow = pkv;
      }
    }
  }
}

// ---------------------------------------------------------------------------
// MFMA flash attention on the flat QKV buffer [M][1152] (Q|K|V sections,
// head dims stored pih-permuted — Q,K identically so QK^T is invariant;
// V's permuted dims flow to Oc cols, matched by WprojT's k-perm).
// Block = (b*H+h, q-tile of 64 rows), 4 waves; wave w owns a 16-row Q strip.
// LDS stride 72 ushorts -> conflict-free frag reads. V transposed into LDS
// during staging. Output Oc bf16 [M][384] concat (stored-position order).
// ---------------------------------------------------------------------------
__global__ __launch_bounds__(256) void attn_kernel(
    const ushort* __restrict__ QKV, ushort* __restrict__ Oc) {
  __shared__ ushort Ks[64 * 72];     // [key][dim]
  __shared__ ushort Vt[64 * 72];     // [dim][key]
  __shared__ ushort Pl[4][16 * 72];  // per-wave P strip [row][key]
  const int bh = blockIdx.x, qt = blockIdx.y;
  const int b = bh / Hh, h = bh % Hh;
  const int tid = threadIdx.x;
  const int w = tid >> 6, lane = tid & 63;
  const int g = lane >> 4, n16 = lane & 15;

  const ushort* qrow =
      QKV + (size_t)(b * Tseq + qt * 64 + w * 16 + n16) * Nqkv + h * HSd;
  short8 qf0 = *(const short8*)(qrow + g * 8);
  short8 qf1 = *(const short8*)(qrow + 32 + g * 8);

  f32x4 oacc[4] = {};
  float m_r[4], l_r[4];
#pragma unroll
  for (int r = 0; r < 4; ++r) { m_r[r] = -1e30f; l_r[r] = 0.f; }

  const int t0 = qt * 64 + w * 16 + g * 4;

  const ushort* Ksrc = QKV + (size_t)b * Tseq * Nqkv + Cdim + h * HSd;
  const ushort* Vsrc = QKV + (size_t)b * Tseq * Nqkv + 2 * Cdim + h * HSd;

  for (int st = 0; st <= qt; ++st) {
    __syncthreads();
    for (int c = tid; c < 512; c += 256) {
      int kr = c >> 3, kc = (c & 7) * 8;
      *(uint4*)&Ks[kr * 72 + kc] =
          *(const uint4*)&Ksrc[(size_t)(st * 64 + kr) * Nqkv + kc];
      int vr = c & 63, vc = (c >> 6) * 8;
      uint4 vv = *(const uint4*)&Vsrc[(size_t)(st * 64 + vr) * Nqkv + vc];
      const ushort* pv = (const ushort*)&vv;
#pragma unroll
      for (int i = 0; i < 8; ++i) Vt[(vc + i) * 72 + vr] = pv[i];
    }
    __syncthreads();

    f32x4 s[4];
#pragma unroll
    for (int ct = 0; ct < 4; ++ct) {
      short8 kf0 = *(const short8*)&Ks[(ct * 16 + n16) * 72 + g * 8];
      short8 kf1 = *(const short8*)&Ks[(ct * 16 + n16) * 72 + 32 + g * 8];
      f32x4 z = {};
      z = __builtin_amdgcn_mfma_f32_16x16x32_bf16(qf0, kf0, z, 0, 0, 0);
      z = __builtin_amdgcn_mfma_f32_16x16x32_bf16(qf1, kf1, z, 0, 0, 0);
      s[ct] = z;
    }

#pragma unroll
    for (int ct = 0; ct < 4; ++ct) {
      const int s_col = st * 64 + ct * 16 + n16;
#pragma unroll
      for (int r = 0; r < 4; ++r) {
        float v = s[ct][r] * 0.125f;
        s[ct][r] = (s_col > t0 + r) ? -1e30f : v;
      }
    }

#pragma unroll
    for (int r = 0; r < 4; ++r) {
      float m = fmaxf(fmaxf(s[0][r], s[1][r]), fmaxf(s[2][r], s[3][r]));
      m = fmaxf(m, __shfl_xor(m, 1, 64));
      m = fmaxf(m, __shfl_xor(m, 2, 64));
      m = fmaxf(m, __shfl_xor(m, 4, 64));
      m = fmaxf(m, __shfl_xor(m, 8, 64));
      float mnew = fmaxf(m_r[r], m);
      float alpha = __expf(m_r[r] - mnew);
      m_r[r] = mnew;
      float ssum = 0.f;
#pragma unroll
      for (int ct = 0; ct < 4; ++ct) {
        float p = __expf(s[ct][r] - mnew);
        s[ct][r] = p;
        ssum += p;
      }
      ssum += __shfl_xor(ssum, 1, 64);
      ssum += __shfl_xor(ssum, 2, 64);
      ssum += __shfl_xor(ssum, 4, 64);
      ssum += __shfl_xor(ssum, 8, 64);
      l_r[r] = l_r[r] * alpha + ssum;
#pragma unroll
      for (int j = 0; j < 4; ++j) oacc[j][r] *= alpha;
    }

    ushort* pw = &Pl[w][0];
#pragma unroll
    for (int ct = 0; ct < 4; ++ct)
#pragma unroll
      for (int r = 0; r < 4; ++r)
        pw[(g * 4 + r) * 72 + ct * 16 + n16] = f2bf(s[ct][r]);

    short8 pf0 = *(const short8*)&pw[n16 * 72 + g * 8];
    short8 pf1 = *(const short8*)&pw[n16 * 72 + 32 + g * 8];
#pragma unroll
    for (int j = 0; j < 4; ++j) {
      short8 vf0 = *(const short8*)&Vt[(j * 16 + n16) * 72 + g * 8];
      short8 vf1 = *(const short8*)&Vt[(j * 16 + n16) * 72 + 32 + g * 8];
      oacc[j] = __builtin_amdgcn_mfma_f32_16x16x32_bf16(pf0, vf0, oacc[j], 0, 0, 0);
      oacc[j] = __builtin_amdgcn_mfma_f32_16x16x32_bf16(pf1, vf1, oacc[j], 0, 0, 0);
    }
  }

  float inv[4];
#pragma unroll
  for (int r = 0; r < 4; ++r) inv[r] = 1.f / l_r[r];
  ushort* orow = Oc + ((size_t)(b * Tseq + qt * 64 + w * 16)) * Cdim + h * HSd;
#pragma unroll
  for (int j = 0; j < 4; ++j)
#pragma unroll
    for (int r = 0; r < 4; ++r)
      orow[(size_t)(g * 4 + r) * Cdim + j * 16 + n16] = f2bf(oacc[j][r] * inv[r]);
}

// ---------------------------------------------------------------------------
extern "C" void kernel_launch(void* const* d_in, const int* in_sizes, int n_in,
                              void* d_out, int out_size, void* d_ws, size_t ws_size,
                              hipStream_t stream) {
  const float* x      = (const float*)d_in[0];
  const float* ln1_w  = (const float*)d_in[1];
  const float* ln1_b  = (const float*)d_in[2];
  const float* Wq     = (const float*)d_in[3];
  const float* bq     = (const float*)d_in[4];
  const float* Wk     = (const float*)d_in[5];
  const float* bk     = (const float*)d_in[6];
  const float* Wv     = (const float*)d_in[7];
  const float* bv     = (const float*)d_in[8];
  const float* Wproj  = (const float*)d_in[9];
  const float* bproj  = (const float*)d_in[10];
  const float* ln2_w  = (const float*)d_in[11];
  const float* ln2_b  = (const float*)d_in[12];
  const float* W1     = (const float*)d_in[13];
  const float* b1     = (const float*)d_in[14];
  const float* W2     = (const float*)d_in[15];
  const float* b2     = (const float*)d_in[16];
  float* out = (float*)d_out;

  // Workspace layout (~110 MB). QKV is one flat [M][1152] bf16 buffer;
  // x1 aliases it (QKV dead after attn; proj writes x1 afterwards).
  char* p = (char*)d_ws;
  ushort* h     = (ushort*)p;  p += (size_t)Mrows * Cdim * 2;
  ushort* QKV   = (ushort*)p;  p += (size_t)Mrows * Nqkv * 2;   // x1 aliases
  ushort* Oc    = (ushort*)p;  p += (size_t)Mrows * Cdim * 2;
  ushort* g     = (ushort*)p;  p += (size_t)Mrows * Cffn * 2;
  ushort* WqkvT = (ushort*)p;  p += (size_t)Nqkv * Cdim * 2;
  ushort* WprojT= (ushort*)p;  p += (size_t)Cdim * Cdim * 2;
  ushort* W1T   = (ushort*)p;  p += (size_t)Cffn * Cdim * 2;
  ushort* W2T   = (ushort*)p;  p += (size_t)Cdim * Cffn * 2;
  float*  bqkv  = (float*)p;   p += (size_t)Nqkv * 4;
  float*  sCol  = (float*)p;   p += (size_t)Cffn * 4;
  float*  c2b   = (float*)p;   p += (size_t)Cffn * 4;
  float2* stats = (float2*)p;  p += (size_t)Mrows * sizeof(float2);
  ushort* x1 = QKV;

  dim3 blk(256);

  // 0. Fused weight prep (transpose-casts + k-perms + LN2-fold precompute)
  prep_kernel<<<dim3(1739), blk, 0, stream>>>(Wq, Wk, Wv, Wproj, W1, W2,
                                              bq, bk, bv, ln2_w, ln2_b, b1,
                                              WqkvT, WprojT, W1T, W2T,
                                              bqkv, sCol, c2b);

  // 1. LN1 -> h (bf16)
  ln_kernel<float><<<dim3(Mrows / 4), blk, 0, stream>>>(x, ln1_w, ln1_b, h, Mrows);

  // 2. QKV fused GEMM -> flat [M][1152], per-head pih-permuted dims
  mfma_gemm<3, 128><<<dim3(Nqkv / 128, Mrows / 128), blk, 0, stream>>>(
      h, WqkvT, bqkv, nullptr, QKV, nullptr, nullptr, Mrows, Nqkv, Cdim);

  // 3. MFMA flash attention -> Oc (bf16, concat layout)
  attn_kernel<<<dim3(Bsz * Hh, 4), blk, 0, stream>>>(QKV, Oc);

  // 4. x1 = x + Oc @ Wproj + bproj -> bf16 (skinny N: BN=64)
  mfma_gemm<1, 64><<<dim3(Cdim / 64, Mrows / 128), blk, 0, stream>>>(
      Oc, WprojT, bproj, x, x1, nullptr, nullptr, Mrows, Cdim, Cdim);

  // 5. LN2 stats only (fold): {rstd, rstd*mean} per row of x1
  stats_kernel<<<dim3(Mrows / 4), blk, 0, stream>>>(x1, stats, Mrows);

  // 6. g = gelu(LN2(x1) @ W1 + b1) via fold: A=x1, W1T pre-scaled by ln2_w,
  //    epilogue applies rstd*acc - rstd*mean*s_n + c2b_n. pih-permuted g.
  mfma_gemm<5, 128><<<dim3(Cffn / 128, Mrows / 128), blk, 0, stream>>>(
      x1, W1T, c2b, stats, g, sCol, nullptr, Mrows, Cffn, Cdim);

  // 7. out = x1 + g @ W2 + b2 -> fp32 (bf16 residual; W2T pih-matched)
  mfma_gemm<4, 64><<<dim3(Cdim / 64, Mrows / 128), blk, 0, stream>>>(
      g, W2T, b2, x1, out, nullptr, nullptr, Mrows, Cdim, Cffn);
}

// Round 10
// 241.444 us; speedup vs baseline: 1.0889x; 1.0889x over previous
//
#include <hip/hip_runtime.h>
#include <math.h>

// Problem constants
constexpr int Bsz  = 64;
constexpr int Tseq = 256;
constexpr int Cdim = 384;
constexpr int Hh   = 6;
constexpr int HSd  = 64;
constexpr int Mrows = Bsz * Tseq;        // 16384
constexpr int Cffn  = 4 * Cdim;          // 1536
constexpr int Nqkv  = 3 * Cdim;          // 1152

typedef __attribute__((ext_vector_type(8))) short short8;  // 8 bf16 = 4 VGPRs
typedef __attribute__((ext_vector_type(4))) float f32x4;

// fp32 -> bf16 round-to-nearest-even
__device__ __forceinline__ ushort f2bf(float x) {
  union { float f; uint u; } a; a.f = x;
  uint r = a.u + 0x7fffu + ((a.u >> 16) & 1u);
  return (ushort)(r >> 16);
}
__device__ __forceinline__ float bf2f(ushort u) {
  union { uint u; float f; } a; a.u = ((uint)u) << 16;
  return a.f;
}
// Pack 2 f32 -> 2 bf16 (RNE) in one instruction (T12 recipe, no builtin).
__device__ __forceinline__ uint pk_bf16(float lo, float hi) {
  uint r;
  asm("v_cvt_pk_bf16_f32 %0, %1, %2" : "=v"(r) : "v"(lo), "v"(hi));
  return r;
}

// Fast GELU (tanh form): ~3e-4 max error vs exact-erf, ~8 VALU ops vs ~25.
__device__ __forceinline__ float gelu_fast(float x) {
  float t = x * x;
  float u = x * fmaf(0.044715f, t, 1.0f);
  float e = fminf(1.5957691216f * u, 80.f);
  float z = __expf(e);
  return x * (z / (1.0f + z));
}

// ---------------------------------------------------------------------------
// Fused prep + LN1, one launch (R16: prep and LN1 are data-independent;
// merging overlaps the 25 MB LN1 read under the weight transposes and drops
// one launch gap). Blocks 0..1727 = 32x32 transpose tiles; 1728..1732 bias
// concat; 1733..5828 = LN1 rows (4 rows per block, wave per row).
// pih(c) = (c & ~63) + (c&15)*4 + ((c>>4)&3) k-permutation applied to:
// Wproj k-axis (matches QKV EPI=3 store) and W2 k-axis (matches FFN1 EPI=2
// store). Per-64-block only (R5's row-wide perm broke store coalescing).
// GEMMs contract sum_k A[m][k]*B[n][k]; permuting k identically on both
// operands leaves the product invariant.
// ---------------------------------------------------------------------------
__global__ __launch_bounds__(256) void prep_kernel(
    const float* __restrict__ Wq, const float* __restrict__ Wk,
    const float* __restrict__ Wv, const float* __restrict__ Wproj,
    const float* __restrict__ W1, const float* __restrict__ W2,
    const float* __restrict__ bq, const float* __restrict__ bk,
    const float* __restrict__ bv,
    const float* __restrict__ x, const float* __restrict__ ln1_w,
    const float* __restrict__ ln1_b,
    ushort* __restrict__ WqkvT, ushort* __restrict__ WprojT,
    ushort* __restrict__ W1T, ushort* __restrict__ W2T,
    float* __restrict__ bqkv, ushort* __restrict__ hOut) {
  const int bid = blockIdx.x;
  if (bid >= 1733) {  // -------- LN1: 4 rows per block --------
    const int row  = (bid - 1733) * 4 + (threadIdx.x >> 6);
    const int lane = threadIdx.x & 63;
    if (row >= Mrows) return;
    const float* xr = x + (size_t)row * Cdim;
    float v[6];
    float s = 0.f;
#pragma unroll
    for (int i = 0; i < 6; ++i) { v[i] = xr[lane + 64 * i]; s += v[i]; }
#pragma unroll
    for (int off = 32; off > 0; off >>= 1) s += __shfl_xor(s, off, 64);
    float mean = s * (1.f / Cdim);
    float sq = 0.f;
#pragma unroll
    for (int i = 0; i < 6; ++i) { float d = v[i] - mean; sq += d * d; }
#pragma unroll
    for (int off = 32; off > 0; off >>= 1) sq += __shfl_xor(sq, off, 64);
    float rstd = rsqrtf(sq * (1.f / Cdim) + 1e-5f);
    ushort* orow = hOut + (size_t)row * Cdim;
#pragma unroll
    for (int i = 0; i < 6; ++i) {
      int c = lane + 64 * i;
      orow[c] = f2bf((v[i] - mean) * rstd * ln1_w[c] + ln1_b[c]);
    }
    return;
  }
  if (bid >= 1728) {  // bias concat
    int i = (bid - 1728) * 256 + threadIdx.x;
    if (i < Nqkv)
      bqkv[i] = (i < 384) ? bq[i] : (i < 768) ? bk[i - 384] : bv[i - 768];
    return;
  }
  const int tx = threadIdx.x & 31, ty = threadIdx.x >> 5;  // 32 x 8
  const float* src; ushort* dst; int R, S, r0, s0, perm = 0;
  if (bid < 432) {           // Wq/Wk/Wv: [6][384][64] each -> rows of WqkvT
    int which = bid / 144, rem = bid % 144;
    const float* W = (which == 0) ? Wq : (which == 1) ? Wk : Wv;
    int bz = rem / 24, t = rem % 24;
    R = 384; S = 64;
    src = W + (size_t)bz * R * S;
    dst = WqkvT + (size_t)which * 384 * 384 + (size_t)bz * R * S;
    r0 = (t >> 1) * 32; s0 = (t & 1) * 32;
  } else if (bid < 576) {    // Wproj 384x384 (k-axis pih per 64-block)
    int rem = bid - 432; R = 384; S = 384; src = Wproj; dst = WprojT;
    r0 = (rem / 12) * 32; s0 = (rem % 12) * 32; perm = 1;
  } else if (bid < 1152) {   // W1 384x1536
    int rem = bid - 576; R = 384; S = 1536; src = W1; dst = W1T;
    r0 = (rem / 48) * 32; s0 = (rem % 48) * 32;
  } else {                   // W2 1536x384 (k-axis pih per 64-block)
    int rem = bid - 1152; R = 1536; S = 384; src = W2; dst = W2T;
    r0 = (rem / 12) * 32; s0 = (rem % 12) * 32; perm = 1;
  }
  __shared__ float t[32][33];
#pragma unroll
  for (int i = 0; i < 32; i += 8)
    t[ty + i][tx] = src[(size_t)(r0 + ty + i) * S + s0 + tx];
  __syncthreads();
  const int kk = r0 + tx;
  int kp = kk;
  if (perm) kp = (kk & ~63) | (((kk & 15) << 2) | ((kk >> 4) & 3));
#pragma unroll
  for (int i = 0; i < 32; i += 8)
    dst[(size_t)(s0 + ty + i) * R + kp] = f2bf(t[tx][ty + i]);
}

// ---------------------------------------------------------------------------
// LayerNorm: one wave per row of 384; 4 rows per block. bf16 output.
// T = float (unused now) or ushort (LN2 on bf16 x1).
// ---------------------------------------------------------------------------
template <typename T>
__global__ __launch_bounds__(256) void ln_kernel(
    const T* __restrict__ x, const float* __restrict__ w,
    const float* __restrict__ b, ushort* __restrict__ out, int nrows) {
  int row  = blockIdx.x * 4 + (threadIdx.x >> 6);
  int lane = threadIdx.x & 63;
  if (row >= nrows) return;
  const T* xr = x + (size_t)row * Cdim;
  float v[6];
  float s = 0.f;
#pragma unroll
  for (int i = 0; i < 6; ++i) {
    if constexpr (sizeof(T) == 2) v[i] = bf2f(xr[lane + 64 * i]);
    else                          v[i] = xr[lane + 64 * i];
    s += v[i];
  }
#pragma unroll
  for (int off = 32; off > 0; off >>= 1) s += __shfl_xor(s, off, 64);
  float mean = s * (1.f / Cdim);
  float sq = 0.f;
#pragma unroll
  for (int i = 0; i < 6; ++i) { float d = v[i] - mean; sq += d * d; }
#pragma unroll
  for (int off = 32; off > 0; off >>= 1) sq += __shfl_xor(sq, off, 64);
  float rstd = rsqrtf(sq * (1.f / Cdim) + 1e-5f);
  ushort* orow = out + (size_t)row * Cdim;
#pragma unroll
  for (int i = 0; i < 6; ++i) {
    int c = lane + 64 * i;
    orow[c] = f2bf((v[i] - mean) * rstd * w[c] + b[c]);
  }
}

// ---------------------------------------------------------------------------
// bf16 MFMA GEMM: C[M,N] = epi(A[M,K] @ Bt[N,K]^T + bias). 128xBN tile, BK=64.
// Loop = R1/R7 structure (best measured across R1/R4/R8/R9 experiments):
// dbuf LDS + counted-vmcnt pipeline.
//   stage(t+1 -> buf^1); vmcnt(LPT); barrier;   // tile t landed, t+1 in flight
//   ds_read+MFMA on buf; lgkmcnt(0); barrier.
// Epilogues: EPI 2/3 emit v_cvt_pk_bf16_f32 pairs + dwordx2 stores into
// PER-64-BLOCK pih-permuted layouts; per (i,r) each 16-lane group stores one
// contiguous 128 B run.
// LDS [buf][row][64], XOR chunk swizzle slot=(c&7)^(row&7); readers use
// quad (half*4+g)^(lm&7) -> all 8 bank-quads, 2-way (free, m136).
// XCD swizzle requires gridDim.y==128.
// EPI: 1 = +bias+res(fp32) -> bf16 (proj -> x1)
//      2 = gelu -> bf16, per-64-block pih-permuted g (FFN1)
//      3 = QKV flat [M][1152], per-head pih-permuted dims
//      4 = +bias+res(bf16) -> fp32 (FFN2 -> out)
// ---------------------------------------------------------------------------
template <int EPI, int BN>
__global__ __launch_bounds__(256) void mfma_gemm(
    const ushort* __restrict__ A, const ushort* __restrict__ Bt,
    const float* __restrict__ bias, const void* __restrict__ res,
    void* __restrict__ Cout, void* __restrict__ C2, void* __restrict__ C3,
    int M, int N, int K) {
  constexpr int WC = BN / 2;    // wave col span
  constexpr int JN = WC / 16;   // col frags per wave (4 or 2)
  constexpr int NB = BN / 32;   // B staging chunks per thread (4 or 2)
  __shared__ ushort Als[2 * 128 * 64];
  __shared__ ushort Bls[2 * BN * 64];
  const int tid = threadIdx.x;

  // XCD-aware remap (requires gridDim.y == 128)
  const int lid = blockIdx.y * gridDim.x + blockIdx.x;
  const int xcd = lid & 7, idx = lid >> 3;
  const int by = xcd * 16 + (idx & 15);
  const int bx = idx >> 4;
  const int m0 = by * 128, n0 = bx * BN;

  const int lane = tid & 63;
  const int w    = tid >> 6;
  const int wr   = (w >> 1) * 64;
  const int wc   = (w & 1) * WC;
  const int lm   = lane & 15;
  const int g    = lane >> 4;
  const int rq   = g * 4;

  const int wub = (tid & ~63) * 8;  // wave-uniform ushort offset of lane 0

  f32x4 acc[4][JN] = {};

  // Stage one BK=64 tile into LDS buffer `bf`.
  auto stage = [&](int k0, int bf) {
    ushort* Ab = Als + bf * (128 * 64);
    ushort* Bb = Bls + bf * (BN * 64);
#pragma unroll
    for (int q = 0; q < 4; ++q) {    // A: 128 rows x 8 chunks = 1024
      const int ci = tid + q * 256;
      const int row = ci >> 3;
      const int kc = ((ci & 7) ^ (row & 7)) * 8;
      const ushort* gA = A + (size_t)(m0 + row) * K + k0 + kc;
      __builtin_amdgcn_global_load_lds(
          (const __attribute__((address_space(1))) uint*)gA,
          (__attribute__((address_space(3))) uint*)(Ab + wub + q * 2048),
          16, 0, 0);
    }
#pragma unroll
    for (int q = 0; q < NB; ++q) {   // B: BN rows x 8 chunks
      const int ci = tid + q * 256;
      const int row = ci >> 3;
      const int kc = ((ci & 7) ^ (row & 7)) * 8;
      const ushort* gB = Bt + (size_t)(n0 + row) * K + k0 + kc;
      __builtin_amdgcn_global_load_lds(
          (const __attribute__((address_space(1))) uint*)gB,
          (__attribute__((address_space(3))) uint*)(Bb + wub + q * 2048),
          16, 0, 0);
    }
  };

  const int nt = K >> 6;
  stage(0, 0);

  for (int t = 0; t < nt; ++t) {
    const int cur = t & 1;
    if (t + 1 < nt) {
      stage((t + 1) * 64, cur ^ 1);
      // Wait only tile t's loads; the newest LPT (tile t+1) stay in flight.
      if constexpr (NB == 4)
        asm volatile("s_waitcnt vmcnt(8)" ::: "memory");
      else
        asm volatile("s_waitcnt vmcnt(6)" ::: "memory");
    } else {
      asm volatile("s_waitcnt vmcnt(0)" ::: "memory");
    }
    __builtin_amdgcn_sched_barrier(0);
    __builtin_amdgcn_s_barrier();      // everyone's tile-t loads landed
    __builtin_amdgcn_sched_barrier(0);

    const ushort* Ab = Als + cur * (128 * 64);
    const ushort* Bb = Bls + cur * (BN * 64);
#pragma unroll
    for (int half = 0; half < 2; ++half) {
      const int sl = ((half << 2) | g) ^ (lm & 7);  // swizzled chunk slot
      short8 af[4], bfr[JN];
#pragma unroll
      for (int i = 0; i < 4; ++i)
        af[i] = *(const short8*)&Ab[(wr + i * 16 + lm) * 64 + sl * 8];
#pragma unroll
      for (int j = 0; j < JN; ++j)
        bfr[j] = *(const short8*)&Bb[(wc + j * 16 + lm) * 64 + sl * 8];
      __builtin_amdgcn_s_setprio(1);
#pragma unroll
      for (int i = 0; i < 4; ++i)
#pragma unroll
        for (int j = 0; j < JN; ++j)
          acc[i][j] = __builtin_amdgcn_mfma_f32_16x16x32_bf16(af[i], bfr[j],
                                                              acc[i][j], 0, 0, 0);
      __builtin_amdgcn_s_setprio(0);
    }

    // All ds_reads retired; fence then barrier so next stage may overwrite.
    asm volatile("s_waitcnt lgkmcnt(0)" ::: "memory");
    __builtin_amdgcn_sched_barrier(0);
    __builtin_amdgcn_s_barrier();
    __builtin_amdgcn_sched_barrier(0);
  }

  float bb[JN];
#pragma unroll
  for (int j = 0; j < JN; ++j) bb[j] = bias[n0 + wc + j * 16 + lm];

#pragma unroll
  for (int i = 0; i < 4; ++i) {
#pragma unroll
    for (int r = 0; r < 4; ++r) {
      const int row = m0 + wr + i * 16 + rq + r;
      if constexpr (EPI == 1) {        // + fp32 residual -> bf16 out (true layout)
        const float* resrow = (const float*)res + (size_t)row * N + n0 + wc;
        ushort* crow = (ushort*)Cout + (size_t)row * N + n0 + wc;
#pragma unroll
        for (int j = 0; j < JN; ++j) {
          float rv = __builtin_nontemporal_load(resrow + j * 16 + lm);
          crow[j * 16 + lm] = f2bf(acc[i][j][r] + bb[j] + rv);
        }
      } else if constexpr (EPI == 4) { // + bf16 residual -> fp32 out
        const ushort* resrow = (const ushort*)res + (size_t)row * N + n0 + wc;
        float* crow = (float*)Cout + (size_t)row * N + n0 + wc;
#pragma unroll
        for (int j = 0; j < JN; ++j)
          crow[j * 16 + lm] = acc[i][j][r] + bb[j] + bf2f(resrow[j * 16 + lm]);
      } else if constexpr (EPI == 3) { // QKV flat, per-head pih perm (JN==4)
        // true col c = n0+wc+j*16+lm; head base hb = n0+wc; d = j*16+lm;
        // stored at hb + pih(d) = hb + lm*4 + j  -> 4 consecutive ushorts.
        ushort* crow = (ushort*)Cout + (size_t)row * N + n0 + wc + lm * 4;
        uint d0 = pk_bf16(acc[i][0][r] + bb[0], acc[i][1][r] + bb[1]);
        uint d1 = pk_bf16(acc[i][2][r] + bb[2], acc[i][3][r] + bb[3]);
        uint2 pkv; pkv.x = d0; pkv.y = d1;
        *(uint2*)crow = pkv;
      } else {                         // EPI == 2: gelu -> per-64-block pih g
        // Same addressing as EPI 3: stored at (n0+wc) + lm*4 + j.
        ushort* crow = (ushort*)Cout + (size_t)row * N + n0 + wc + lm * 4;
        float g0 = gelu_fast(acc[i][0][r] + bb[0]);
        float g1 = gelu_fast(acc[i][1][r] + bb[1]);
        float g2 = gelu_fast(acc[i][2][r] + bb[2]);
        float g3 = gelu_fast(acc[i][3][r] + bb[3]);
        uint d0 = pk_bf16(g0, g1);
        uint d1 = pk_bf16(g2, g3);
        uint2 pkv; pkv.x = d0; pkv.y = d1;
        *(uint2*)crow = pkv;
      }
    }
  }
}

// ---------------------------------------------------------------------------
// MFMA flash attention on the flat QKV buffer [M][1152] (Q|K|V sections,
// head dims stored pih-permuted — Q,K identically so QK^T is invariant;
// V's permuted dims flow to Oc cols, matched by WprojT's k-perm).
// Block = (b*H+h, q-tile of 64 rows), 4 waves; wave w owns a 16-row Q strip.
// LDS stride 72 ushorts -> conflict-free frag reads. V transposed into LDS
// during staging. Output Oc bf16 [M][384] concat (stored-position order).
// ---------------------------------------------------------------------------
__global__ __launch_bounds__(256) void attn_kernel(
    const ushort* __restrict__ QKV, ushort* __restrict__ Oc) {
  __shared__ ushort Ks[64 * 72];     // [key][dim]
  __shared__ ushort Vt[64 * 72];     // [dim][key]
  __shared__ ushort Pl[4][16 * 72];  // per-wave P strip [row][key]
  const int bh = blockIdx.x, qt = blockIdx.y;
  const int b = bh / Hh, h = bh % Hh;
  const int tid = threadIdx.x;
  const int w = tid >> 6, lane = tid & 63;
  const int g = lane >> 4, n16 = lane & 15;

  const ushort* qrow =
      QKV + (size_t)(b * Tseq + qt * 64 + w * 16 + n16) * Nqkv + h * HSd;
  short8 qf0 = *(const short8*)(qrow + g * 8);
  short8 qf1 = *(const short8*)(qrow + 32 + g * 8);

  f32x4 oacc[4] = {};
  float m_r[4], l_r[4];
#pragma unroll
  for (int r = 0; r < 4; ++r) { m_r[r] = -1e30f; l_r[r] = 0.f; }

  const int t0 = qt * 64 + w * 16 + g * 4;

  const ushort* Ksrc = QKV + (size_t)b * Tseq * Nqkv + Cdim + h * HSd;
  const ushort* Vsrc = QKV + (size_t)b * Tseq * Nqkv + 2 * Cdim + h * HSd;

  for (int st = 0; st <= qt; ++st) {
    __syncthreads();
    for (int c = tid; c < 512; c += 256) {
      int kr = c >> 3, kc = (c & 7) * 8;
      *(uint4*)&Ks[kr * 72 + kc] =
          *(const uint4*)&Ksrc[(size_t)(st * 64 + kr) * Nqkv + kc];
      int vr = c & 63, vc = (c >> 6) * 8;
      uint4 vv = *(const uint4*)&Vsrc[(size_t)(st * 64 + vr) * Nqkv + vc];
      const ushort* pv = (const ushort*)&vv;
#pragma unroll
      for (int i = 0; i < 8; ++i) Vt[(vc + i) * 72 + vr] = pv[i];
    }
    __syncthreads();

    f32x4 s[4];
#pragma unroll
    for (int ct = 0; ct < 4; ++ct) {
      short8 kf0 = *(const short8*)&Ks[(ct * 16 + n16) * 72 + g * 8];
      short8 kf1 = *(const short8*)&Ks[(ct * 16 + n16) * 72 + 32 + g * 8];
      f32x4 z = {};
      z = __builtin_amdgcn_mfma_f32_16x16x32_bf16(qf0, kf0, z, 0, 0, 0);
      z = __builtin_amdgcn_mfma_f32_16x16x32_bf16(qf1, kf1, z, 0, 0, 0);
      s[ct] = z;
    }

#pragma unroll
    for (int ct = 0; ct < 4; ++ct) {
      const int s_col = st * 64 + ct * 16 + n16;
#pragma unroll
      for (int r = 0; r < 4; ++r) {
        float v = s[ct][r] * 0.125f;
        s[ct][r] = (s_col > t0 + r) ? -1e30f : v;
      }
    }

#pragma unroll
    for (int r = 0; r < 4; ++r) {
      float m = fmaxf(fmaxf(s[0][r], s[1][r]), fmaxf(s[2][r], s[3][r]));
      m = fmaxf(m, __shfl_xor(m, 1, 64));
      m = fmaxf(m, __shfl_xor(m, 2, 64));
      m = fmaxf(m, __shfl_xor(m, 4, 64));
      m = fmaxf(m, __shfl_xor(m, 8, 64));
      float mnew = fmaxf(m_r[r], m);
      float alpha = __expf(m_r[r] - mnew);
      m_r[r] = mnew;
      float ssum = 0.f;
#pragma unroll
      for (int ct = 0; ct < 4; ++ct) {
        float p = __expf(s[ct][r] - mnew);
        s[ct][r] = p;
        ssum += p;
      }
      ssum += __shfl_xor(ssum, 1, 64);
      ssum += __shfl_xor(ssum, 2, 64);
      ssum += __shfl_xor(ssum, 4, 64);
      ssum += __shfl_xor(ssum, 8, 64);
      l_r[r] = l_r[r] * alpha + ssum;
#pragma unroll
      for (int j = 0; j < 4; ++j) oacc[j][r] *= alpha;
    }

    ushort* pw = &Pl[w][0];
#pragma unroll
    for (int ct = 0; ct < 4; ++ct)
#pragma unroll
      for (int r = 0; r < 4; ++r)
        pw[(g * 4 + r) * 72 + ct * 16 + n16] = f2bf(s[ct][r]);

    short8 pf0 = *(const short8*)&pw[n16 * 72 + g * 8];
    short8 pf1 = *(const short8*)&pw[n16 * 72 + 32 + g * 8];
#pragma unroll
    for (int j = 0; j < 4; ++j) {
      short8 vf0 = *(const short8*)&Vt[(j * 16 + n16) * 72 + g * 8];
      short8 vf1 = *(const short8*)&Vt[(j * 16 + n16) * 72 + 32 + g * 8];
      oacc[j] = __builtin_amdgcn_mfma_f32_16x16x32_bf16(pf0, vf0, oacc[j], 0, 0, 0);
      oacc[j] = __builtin_amdgcn_mfma_f32_16x16x32_bf16(pf1, vf1, oacc[j], 0, 0, 0);
    }
  }

  float inv[4];
#pragma unroll
  for (int r = 0; r < 4; ++r) inv[r] = 1.f / l_r[r];
  ushort* orow = Oc + ((size_t)(b * Tseq + qt * 64 + w * 16)) * Cdim + h * HSd;
#pragma unroll
  for (int j = 0; j < 4; ++j)
#pragma unroll
    for (int r = 0; r < 4; ++r)
      orow[(size_t)(g * 4 + r) * Cdim + j * 16 + n16] = f2bf(oacc[j][r] * inv[r]);
}

// ---------------------------------------------------------------------------
extern "C" void kernel_launch(void* const* d_in, const int* in_sizes, int n_in,
                              void* d_out, int out_size, void* d_ws, size_t ws_size,
                              hipStream_t stream) {
  const float* x      = (const float*)d_in[0];
  const float* ln1_w  = (const float*)d_in[1];
  const float* ln1_b  = (const float*)d_in[2];
  const float* Wq     = (const float*)d_in[3];
  const float* bq     = (const float*)d_in[4];
  const float* Wk     = (const float*)d_in[5];
  const float* bk     = (const float*)d_in[6];
  const float* Wv     = (const float*)d_in[7];
  const float* bv     = (const float*)d_in[8];
  const float* Wproj  = (const float*)d_in[9];
  const float* bproj  = (const float*)d_in[10];
  const float* ln2_w  = (const float*)d_in[11];
  const float* ln2_b  = (const float*)d_in[12];
  const float* W1     = (const float*)d_in[13];
  const float* b1     = (const float*)d_in[14];
  const float* W2     = (const float*)d_in[15];
  const float* b2     = (const float*)d_in[16];
  float* out = (float*)d_out;

  // Workspace layout (~110 MB). QKV is one flat [M][1152] bf16 buffer;
  // x1 aliases it (QKV dead after attn; proj writes x1 afterwards).
  char* p = (char*)d_ws;
  ushort* h     = (ushort*)p;  p += (size_t)Mrows * Cdim * 2;   // reused as h2
  ushort* QKV   = (ushort*)p;  p += (size_t)Mrows * Nqkv * 2;   // x1 aliases
  ushort* Oc    = (ushort*)p;  p += (size_t)Mrows * Cdim * 2;
  ushort* g     = (ushort*)p;  p += (size_t)Mrows * Cffn * 2;
  ushort* WqkvT = (ushort*)p;  p += (size_t)Nqkv * Cdim * 2;
  ushort* WprojT= (ushort*)p;  p += (size_t)Cdim * Cdim * 2;
  ushort* W1T   = (ushort*)p;  p += (size_t)Cffn * Cdim * 2;
  ushort* W2T   = (ushort*)p;  p += (size_t)Cdim * Cffn * 2;
  float*  bqkv  = (float*)p;   p += (size_t)Nqkv * 4;
  ushort* h2 = h;
  ushort* x1 = QKV;

  dim3 blk(256);

  // 0. Fused weight prep + LN1 (one launch; prep blocks 0..1732, LN1
  //    blocks 1733..5828 — independent work co-scheduled across CUs)
  prep_kernel<<<dim3(1733 + Mrows / 4), blk, 0, stream>>>(
      Wq, Wk, Wv, Wproj, W1, W2, bq, bk, bv, x, ln1_w, ln1_b,
      WqkvT, WprojT, W1T, W2T, bqkv, h);

  // 1. QKV fused GEMM -> flat [M][1152], per-head pih-permuted dims
  mfma_gemm<3, 128><<<dim3(Nqkv / 128, Mrows / 128), blk, 0, stream>>>(
      h, WqkvT, bqkv, nullptr, QKV, nullptr, nullptr, Mrows, Nqkv, Cdim);

  // 2. MFMA flash attention -> Oc (bf16, concat layout)
  attn_kernel<<<dim3(Bsz * Hh, 4), blk, 0, stream>>>(QKV, Oc);

  // 3. x1 = x + Oc @ Wproj + bproj -> bf16 (skinny N: BN=64)
  mfma_gemm<1, 64><<<dim3(Cdim / 64, Mrows / 128), blk, 0, stream>>>(
      Oc, WprojT, bproj, x, x1, nullptr, nullptr, Mrows, Cdim, Cdim);

  // 4. LN2 -> h2 (bf16, reads bf16 x1)
  ln_kernel<ushort><<<dim3(Mrows / 4), blk, 0, stream>>>(x1, ln2_w, ln2_b, h2, Mrows);

  // 5. g = gelu(h2 @ W1 + b1), per-64-block pih-permuted layout (bf16)
  mfma_gemm<2, 128><<<dim3(Cffn / 128, Mrows / 128), blk, 0, stream>>>(
      h2, W1T, b1, nullptr, g, nullptr, nullptr, Mrows, Cffn, Cdim);

  // 6. out = x1 + g @ W2 + b2 -> fp32 (bf16 residual; W2T pih-matched)
  mfma_gemm<4, 64><<<dim3(Cdim / 64, Mrows / 128), blk, 0, stream>>>(
      g, W2T, b2, x1, out, nullptr, nullptr, Mrows, Cdim, Cffn);
}

// Round 11
// 236.117 us; speedup vs baseline: 1.1134x; 1.0226x over previous
//
#include <hip/hip_runtime.h>
#include <math.h>

// Problem constants
constexpr int Bsz  = 64;
constexpr int Tseq = 256;
constexpr int Cdim = 384;
constexpr int Hh   = 6;
constexpr int HSd  = 64;
constexpr int Mrows = Bsz * Tseq;        // 16384
constexpr int Cffn  = 4 * Cdim;          // 1536
constexpr int Nqkv  = 3 * Cdim;          // 1152

typedef __attribute__((ext_vector_type(8))) short short8;  // 8 bf16 = 4 VGPRs
typedef __attribute__((ext_vector_type(4))) float f32x4;

// fp32 -> bf16 round-to-nearest-even
__device__ __forceinline__ ushort f2bf(float x) {
  union { float f; uint u; } a; a.f = x;
  uint r = a.u + 0x7fffu + ((a.u >> 16) & 1u);
  return (ushort)(r >> 16);
}
__device__ __forceinline__ float bf2f(ushort u) {
  union { uint u; float f; } a; a.u = ((uint)u) << 16;
  return a.f;
}
// Pack 2 f32 -> 2 bf16 (RNE) in one instruction (T12 recipe, no builtin).
__device__ __forceinline__ uint pk_bf16(float lo, float hi) {
  uint r;
  asm("v_cvt_pk_bf16_f32 %0, %1, %2" : "=v"(r) : "v"(lo), "v"(hi));
  return r;
}

// Fast GELU (tanh form): ~3e-4 max error vs exact-erf, ~8 VALU ops vs ~25.
__device__ __forceinline__ float gelu_fast(float x) {
  float t = x * x;
  float u = x * fmaf(0.044715f, t, 1.0f);
  float e = fminf(1.5957691216f * u, 80.f);
  float z = __expf(e);
  return x * (z / (1.0f + z));
}

// ---------------------------------------------------------------------------
// Fused prep + LN1, one launch (R10 win). Blocks 0..1727 = 32x32 transpose
// tiles; 1728..1732 bias concat; 1733..5828 = LN1 rows (4 rows per block).
// pih(c) = (c & ~63) + (c&15)*4 + ((c>>4)&3) k-permutation applied to
// Wproj k-axis (matches QKV EPI=3 store) and W2 k-axis (matches FFN1 EPI=2
// store). Per-64-block only (row-wide perm broke store coalescing, R5).
// ---------------------------------------------------------------------------
__global__ __launch_bounds__(256) void prep_kernel(
    const float* __restrict__ Wq, const float* __restrict__ Wk,
    const float* __restrict__ Wv, const float* __restrict__ Wproj,
    const float* __restrict__ W1, const float* __restrict__ W2,
    const float* __restrict__ bq, const float* __restrict__ bk,
    const float* __restrict__ bv,
    const float* __restrict__ x, const float* __restrict__ ln1_w,
    const float* __restrict__ ln1_b,
    ushort* __restrict__ WqkvT, ushort* __restrict__ WprojT,
    ushort* __restrict__ W1T, ushort* __restrict__ W2T,
    float* __restrict__ bqkv, ushort* __restrict__ hOut) {
  const int bid = blockIdx.x;
  if (bid >= 1733) {  // -------- LN1: 4 rows per block --------
    const int row  = (bid - 1733) * 4 + (threadIdx.x >> 6);
    const int lane = threadIdx.x & 63;
    if (row >= Mrows) return;
    const float* xr = x + (size_t)row * Cdim;
    float v[6];
    float s = 0.f;
#pragma unroll
    for (int i = 0; i < 6; ++i) { v[i] = xr[lane + 64 * i]; s += v[i]; }
#pragma unroll
    for (int off = 32; off > 0; off >>= 1) s += __shfl_xor(s, off, 64);
    float mean = s * (1.f / Cdim);
    float sq = 0.f;
#pragma unroll
    for (int i = 0; i < 6; ++i) { float d = v[i] - mean; sq += d * d; }
#pragma unroll
    for (int off = 32; off > 0; off >>= 1) sq += __shfl_xor(sq, off, 64);
    float rstd = rsqrtf(sq * (1.f / Cdim) + 1e-5f);
    ushort* orow = hOut + (size_t)row * Cdim;
#pragma unroll
    for (int i = 0; i < 6; ++i) {
      int c = lane + 64 * i;
      orow[c] = f2bf((v[i] - mean) * rstd * ln1_w[c] + ln1_b[c]);
    }
    return;
  }
  if (bid >= 1728) {  // bias concat
    int i = (bid - 1728) * 256 + threadIdx.x;
    if (i < Nqkv)
      bqkv[i] = (i < 384) ? bq[i] : (i < 768) ? bk[i - 384] : bv[i - 768];
    return;
  }
  const int tx = threadIdx.x & 31, ty = threadIdx.x >> 5;  // 32 x 8
  const float* src; ushort* dst; int R, S, r0, s0, perm = 0;
  if (bid < 432) {           // Wq/Wk/Wv: [6][384][64] each -> rows of WqkvT
    int which = bid / 144, rem = bid % 144;
    const float* W = (which == 0) ? Wq : (which == 1) ? Wk : Wv;
    int bz = rem / 24, t = rem % 24;
    R = 384; S = 64;
    src = W + (size_t)bz * R * S;
    dst = WqkvT + (size_t)which * 384 * 384 + (size_t)bz * R * S;
    r0 = (t >> 1) * 32; s0 = (t & 1) * 32;
  } else if (bid < 576) {    // Wproj 384x384 (k-axis pih per 64-block)
    int rem = bid - 432; R = 384; S = 384; src = Wproj; dst = WprojT;
    r0 = (rem / 12) * 32; s0 = (rem % 12) * 32; perm = 1;
  } else if (bid < 1152) {   // W1 384x1536
    int rem = bid - 576; R = 384; S = 1536; src = W1; dst = W1T;
    r0 = (rem / 48) * 32; s0 = (rem % 48) * 32;
  } else {                   // W2 1536x384 (k-axis pih per 64-block)
    int rem = bid - 1152; R = 1536; S = 384; src = W2; dst = W2T;
    r0 = (rem / 12) * 32; s0 = (rem % 12) * 32; perm = 1;
  }
  __shared__ float t[32][33];
#pragma unroll
  for (int i = 0; i < 32; i += 8)
    t[ty + i][tx] = src[(size_t)(r0 + ty + i) * S + s0 + tx];
  __syncthreads();
  const int kk = r0 + tx;
  int kp = kk;
  if (perm) kp = (kk & ~63) | (((kk & 15) << 2) | ((kk >> 4) & 3));
#pragma unroll
  for (int i = 0; i < 32; i += 8)
    dst[(size_t)(s0 + ty + i) * R + kp] = f2bf(t[tx][ty + i]);
}

// ---------------------------------------------------------------------------
// LayerNorm (LN2): one wave per row of 384; 4 rows per block. bf16 output.
// ---------------------------------------------------------------------------
template <typename T>
__global__ __launch_bounds__(256) void ln_kernel(
    const T* __restrict__ x, const float* __restrict__ w,
    const float* __restrict__ b, ushort* __restrict__ out, int nrows) {
  int row  = blockIdx.x * 4 + (threadIdx.x >> 6);
  int lane = threadIdx.x & 63;
  if (row >= nrows) return;
  const T* xr = x + (size_t)row * Cdim;
  float v[6];
  float s = 0.f;
#pragma unroll
  for (int i = 0; i < 6; ++i) {
    if constexpr (sizeof(T) == 2) v[i] = bf2f(xr[lane + 64 * i]);
    else                          v[i] = xr[lane + 64 * i];
    s += v[i];
  }
#pragma unroll
  for (int off = 32; off > 0; off >>= 1) s += __shfl_xor(s, off, 64);
  float mean = s * (1.f / Cdim);
  float sq = 0.f;
#pragma unroll
  for (int i = 0; i < 6; ++i) { float d = v[i] - mean; sq += d * d; }
#pragma unroll
  for (int off = 32; off > 0; off >>= 1) sq += __shfl_xor(sq, off, 64);
  float rstd = rsqrtf(sq * (1.f / Cdim) + 1e-5f);
  ushort* orow = out + (size_t)row * Cdim;
#pragma unroll
  for (int i = 0; i < 6; ++i) {
    int c = lane + 64 * i;
    orow[c] = f2bf((v[i] - mean) * rstd * w[c] + b[c]);
  }
}

// ---------------------------------------------------------------------------
// bf16 MFMA GEMM: C[M,N] = epi(A[M,K] @ Bt[N,K]^T + bias). 128xBN tile, BK=64.
// R17: 512-thread / 8-WAVE blocks, same tile. R7-R10 counters: all pipes
// <50%, ~50% of wall with NOTHING issuing (5.7 waves/CU). R8 raised BLOCK
// residency (null); this raises WAVES per block: wave grid 4 row-strips(32)
// x 2 cols, per-wave acc[2][JN] (32/16 AGPR), per-wave work halves, LDS and
// barrier count unchanged -> up to 16-24 waves/CU (4-6/SIMD) to overlap the
// vmcnt/barrier stalls. Counted-vmcnt pipeline preserved exactly:
//   stage(t+1 -> buf^1); vmcnt(LPT); barrier;   // tile t landed, t+1 in flight
//   ds_read+MFMA on buf; lgkmcnt(0); barrier.
// LPT = 4 (BN=128: A 2 + B 2 chunks/thread) or 3 (BN=64: A 2 + B 1).
// LDS [buf][row][64], XOR chunk swizzle slot=(c&7)^(row&7); readers use
// quad (half*4+g)^(lm&7) -> all 8 bank-quads, 2-way (free, m136); per-wave
// read patterns byte-identical to the 4-wave version.
// EPI: 1 = +bias+res(fp32) -> bf16 (proj -> x1)
//      2 = gelu -> bf16, per-64-block pih-permuted g (FFN1)
//      3 = QKV flat [M][1152], per-head pih-permuted dims
//      4 = +bias+res(bf16) -> fp32 (FFN2 -> out)
// XCD swizzle requires gridDim.y==128.
// ---------------------------------------------------------------------------
template <int EPI, int BN>
__global__ __launch_bounds__(512) void mfma_gemm(
    const ushort* __restrict__ A, const ushort* __restrict__ Bt,
    const float* __restrict__ bias, const void* __restrict__ res,
    void* __restrict__ Cout, void* __restrict__ C2, void* __restrict__ C3,
    int M, int N, int K) {
  constexpr int WC  = BN / 2;   // wave col span
  constexpr int JN  = WC / 16;  // col frags per wave (4 or 2)
  constexpr int NBQ = BN / 64;  // B staging passes per thread (2 or 1)
  __shared__ ushort Als[2 * 128 * 64];
  __shared__ ushort Bls[2 * BN * 64];
  const int tid = threadIdx.x;

  // XCD-aware remap (requires gridDim.y == 128)
  const int lid = blockIdx.y * gridDim.x + blockIdx.x;
  const int xcd = lid & 7, idx = lid >> 3;
  const int by = xcd * 16 + (idx & 15);
  const int bx = idx >> 4;
  const int m0 = by * 128, n0 = bx * BN;

  const int lane = tid & 63;
  const int w    = tid >> 6;          // 0..7
  const int wr   = (w & 3) * 32;      // 32-row strip
  const int wc   = (w >> 2) * WC;     // col half
  const int lm   = lane & 15;
  const int g    = lane >> 4;
  const int rq   = g * 4;

  const int wub = (tid & ~63) * 8;  // wave-uniform ushort offset of lane 0

  f32x4 acc[2][JN] = {};

  // Stage one BK=64 tile into LDS buffer `bf` (512 threads).
  auto stage = [&](int k0, int bf) {
    ushort* Ab = Als + bf * (128 * 64);
    ushort* Bb = Bls + bf * (BN * 64);
#pragma unroll
    for (int q = 0; q < 2; ++q) {    // A: 128 rows x 8 chunks = 1024 slots
      const int ci = tid + q * 512;
      const int row = ci >> 3;
      const int kc = ((ci & 7) ^ (row & 7)) * 8;
      const ushort* gA = A + (size_t)(m0 + row) * K + k0 + kc;
      __builtin_amdgcn_global_load_lds(
          (const __attribute__((address_space(1))) uint*)gA,
          (__attribute__((address_space(3))) uint*)(Ab + wub + q * 4096),
          16, 0, 0);
    }
#pragma unroll
    for (int q = 0; q < NBQ; ++q) {  // B: BN rows x 8 chunks
      const int ci = tid + q * 512;
      const int row = ci >> 3;
      const int kc = ((ci & 7) ^ (row & 7)) * 8;
      const ushort* gB = Bt + (size_t)(n0 + row) * K + k0 + kc;
      __builtin_amdgcn_global_load_lds(
          (const __attribute__((address_space(1))) uint*)gB,
          (__attribute__((address_space(3))) uint*)(Bb + wub + q * 4096),
          16, 0, 0);
    }
  };

  const int nt = K >> 6;
  stage(0, 0);

  for (int t = 0; t < nt; ++t) {
    const int cur = t & 1;
    if (t + 1 < nt) {
      stage((t + 1) * 64, cur ^ 1);
      // Wait only tile t's loads; the newest LPT (tile t+1) stay in flight.
      if constexpr (NBQ == 2)
        asm volatile("s_waitcnt vmcnt(4)" ::: "memory");
      else
        asm volatile("s_waitcnt vmcnt(3)" ::: "memory");
    } else {
      asm volatile("s_waitcnt vmcnt(0)" ::: "memory");
    }
    __builtin_amdgcn_sched_barrier(0);
    __builtin_amdgcn_s_barrier();      // everyone's tile-t loads landed
    __builtin_amdgcn_sched_barrier(0);

    const ushort* Ab = Als + cur * (128 * 64);
    const ushort* Bb = Bls + cur * (BN * 64);
#pragma unroll
    for (int half = 0; half < 2; ++half) {
      const int sl = ((half << 2) | g) ^ (lm & 7);  // swizzled chunk slot
      short8 af[2], bfr[JN];
#pragma unroll
      for (int i = 0; i < 2; ++i)
        af[i] = *(const short8*)&Ab[(wr + i * 16 + lm) * 64 + sl * 8];
#pragma unroll
      for (int j = 0; j < JN; ++j)
        bfr[j] = *(const short8*)&Bb[(wc + j * 16 + lm) * 64 + sl * 8];
      __builtin_amdgcn_s_setprio(1);
#pragma unroll
      for (int i = 0; i < 2; ++i)
#pragma unroll
        for (int j = 0; j < JN; ++j)
          acc[i][j] = __builtin_amdgcn_mfma_f32_16x16x32_bf16(af[i], bfr[j],
                                                              acc[i][j], 0, 0, 0);
      __builtin_amdgcn_s_setprio(0);
    }

    // All ds_reads retired; fence then barrier so next stage may overwrite.
    asm volatile("s_waitcnt lgkmcnt(0)" ::: "memory");
    __builtin_amdgcn_sched_barrier(0);
    __builtin_amdgcn_s_barrier();
    __builtin_amdgcn_sched_barrier(0);
  }

  float bb[JN];
#pragma unroll
  for (int j = 0; j < JN; ++j) bb[j] = bias[n0 + wc + j * 16 + lm];

#pragma unroll
  for (int i = 0; i < 2; ++i) {
#pragma unroll
    for (int r = 0; r < 4; ++r) {
      const int row = m0 + wr + i * 16 + rq + r;
      if constexpr (EPI == 1) {        // + fp32 residual -> bf16 out (true layout)
        const float* resrow = (const float*)res + (size_t)row * N + n0 + wc;
        ushort* crow = (ushort*)Cout + (size_t)row * N + n0 + wc;
#pragma unroll
        for (int j = 0; j < JN; ++j) {
          float rv = __builtin_nontemporal_load(resrow + j * 16 + lm);
          crow[j * 16 + lm] = f2bf(acc[i][j][r] + bb[j] + rv);
        }
      } else if constexpr (EPI == 4) { // + bf16 residual -> fp32 out
        const ushort* resrow = (const ushort*)res + (size_t)row * N + n0 + wc;
        float* crow = (float*)Cout + (size_t)row * N + n0 + wc;
#pragma unroll
        for (int j = 0; j < JN; ++j)
          crow[j * 16 + lm] = acc[i][j][r] + bb[j] + bf2f(resrow[j * 16 + lm]);
      } else if constexpr (EPI == 3) { // QKV flat, per-head pih perm (JN==4)
        // true col c = n0+wc+j*16+lm; stored at (n0+wc) + lm*4 + j.
        ushort* crow = (ushort*)Cout + (size_t)row * N + n0 + wc + lm * 4;
        uint d0 = pk_bf16(acc[i][0][r] + bb[0], acc[i][1][r] + bb[1]);
        uint d1 = pk_bf16(acc[i][2][r] + bb[2], acc[i][3][r] + bb[3]);
        uint2 pkv; pkv.x = d0; pkv.y = d1;
        *(uint2*)crow = pkv;
      } else {                         // EPI == 2: gelu -> per-64-block pih g
        ushort* crow = (ushort*)Cout + (size_t)row * N + n0 + wc + lm * 4;
        float g0 = gelu_fast(acc[i][0][r] + bb[0]);
        float g1 = gelu_fast(acc[i][1][r] + bb[1]);
        float g2 = gelu_fast(acc[i][2][r] + bb[2]);
        float g3 = gelu_fast(acc[i][3][r] + bb[3]);
        uint d0 = pk_bf16(g0, g1);
        uint d1 = pk_bf16(g2, g3);
        uint2 pkv; pkv.x = d0; pkv.y = d1;
        *(uint2*)crow = pkv;
      }
    }
  }
}

// ---------------------------------------------------------------------------
// MFMA flash attention on the flat QKV buffer [M][1152] (Q|K|V sections,
// head dims stored pih-permuted — Q,K identically so QK^T is invariant;
// V's permuted dims flow to Oc cols, matched by WprojT's k-perm).
// Block = (b*H+h, q-tile of 64 rows), 4 waves; wave w owns a 16-row Q strip.
// LDS stride 72 ushorts -> conflict-free frag reads. V transposed into LDS
// during staging. Output Oc bf16 [M][384] concat (stored-position order).
// ---------------------------------------------------------------------------
__global__ __launch_bounds__(256) void attn_kernel(
    const ushort* __restrict__ QKV, ushort* __restrict__ Oc) {
  __shared__ ushort Ks[64 * 72];     // [key][dim]
  __shared__ ushort Vt[64 * 72];     // [dim][key]
  __shared__ ushort Pl[4][16 * 72];  // per-wave P strip [row][key]
  const int bh = blockIdx.x, qt = blockIdx.y;
  const int b = bh / Hh, h = bh % Hh;
  const int tid = threadIdx.x;
  const int w = tid >> 6, lane = tid & 63;
  const int g = lane >> 4, n16 = lane & 15;

  const ushort* qrow =
      QKV + (size_t)(b * Tseq + qt * 64 + w * 16 + n16) * Nqkv + h * HSd;
  short8 qf0 = *(const short8*)(qrow + g * 8);
  short8 qf1 = *(const short8*)(qrow + 32 + g * 8);

  f32x4 oacc[4] = {};
  float m_r[4], l_r[4];
#pragma unroll
  for (int r = 0; r < 4; ++r) { m_r[r] = -1e30f; l_r[r] = 0.f; }

  const int t0 = qt * 64 + w * 16 + g * 4;

  const ushort* Ksrc = QKV + (size_t)b * Tseq * Nqkv + Cdim + h * HSd;
  const ushort* Vsrc = QKV + (size_t)b * Tseq * Nqkv + 2 * Cdim + h * HSd;

  for (int st = 0; st <= qt; ++st) {
    __syncthreads();
    for (int c = tid; c < 512; c += 256) {
      int kr = c >> 3, kc = (c & 7) * 8;
      *(uint4*)&Ks[kr * 72 + kc] =
          *(const uint4*)&Ksrc[(size_t)(st * 64 + kr) * Nqkv + kc];
      int vr = c & 63, vc = (c >> 6) * 8;
      uint4 vv = *(const uint4*)&Vsrc[(size_t)(st * 64 + vr) * Nqkv + vc];
      const ushort* pv = (const ushort*)&vv;
#pragma unroll
      for (int i = 0; i < 8; ++i) Vt[(vc + i) * 72 + vr] = pv[i];
    }
    __syncthreads();

    f32x4 s[4];
#pragma unroll
    for (int ct = 0; ct < 4; ++ct) {
      short8 kf0 = *(const short8*)&Ks[(ct * 16 + n16) * 72 + g * 8];
      short8 kf1 = *(const short8*)&Ks[(ct * 16 + n16) * 72 + 32 + g * 8];
      f32x4 z = {};
      z = __builtin_amdgcn_mfma_f32_16x16x32_bf16(qf0, kf0, z, 0, 0, 0);
      z = __builtin_amdgcn_mfma_f32_16x16x32_bf16(qf1, kf1, z, 0, 0, 0);
      s[ct] = z;
    }

#pragma unroll
    for (int ct = 0; ct < 4; ++ct) {
      const int s_col = st * 64 + ct * 16 + n16;
#pragma unroll
      for (int r = 0; r < 4; ++r) {
        float v = s[ct][r] * 0.125f;
        s[ct][r] = (s_col > t0 + r) ? -1e30f : v;
      }
    }

#pragma unroll
    for (int r = 0; r < 4; ++r) {
      float m = fmaxf(fmaxf(s[0][r], s[1][r]), fmaxf(s[2][r], s[3][r]));
      m = fmaxf(m, __shfl_xor(m, 1, 64));
      m = fmaxf(m, __shfl_xor(m, 2, 64));
      m = fmaxf(m, __shfl_xor(m, 4, 64));
      m = fmaxf(m, __shfl_xor(m, 8, 64));
      float mnew = fmaxf(m_r[r], m);
      float alpha = __expf(m_r[r] - mnew);
      m_r[r] = mnew;
      float ssum = 0.f;
#pragma unroll
      for (int ct = 0; ct < 4; ++ct) {
        float p = __expf(s[ct][r] - mnew);
        s[ct][r] = p;
        ssum += p;
      }
      ssum += __shfl_xor(ssum, 1, 64);
      ssum += __shfl_xor(ssum, 2, 64);
      ssum += __shfl_xor(ssum, 4, 64);
      ssum += __shfl_xor(ssum, 8, 64);
      l_r[r] = l_r[r] * alpha + ssum;
#pragma unroll
      for (int j = 0; j < 4; ++j) oacc[j][r] *= alpha;
    }

    ushort* pw = &Pl[w][0];
#pragma unroll
    for (int ct = 0; ct < 4; ++ct)
#pragma unroll
      for (int r = 0; r < 4; ++r)
        pw[(g * 4 + r) * 72 + ct * 16 + n16] = f2bf(s[ct][r]);

    short8 pf0 = *(const short8*)&pw[n16 * 72 + g * 8];
    short8 pf1 = *(const short8*)&pw[n16 * 72 + 32 + g * 8];
#pragma unroll
    for (int j = 0; j < 4; ++j) {
      short8 vf0 = *(const short8*)&Vt[(j * 16 + n16) * 72 + g * 8];
      short8 vf1 = *(const short8*)&Vt[(j * 16 + n16) * 72 + 32 + g * 8];
      oacc[j] = __builtin_amdgcn_mfma_f32_16x16x32_bf16(pf0, vf0, oacc[j], 0, 0, 0);
      oacc[j] = __builtin_amdgcn_mfma_f32_16x16x32_bf16(pf1, vf1, oacc[j], 0, 0, 0);
    }
  }

  float inv[4];
#pragma unroll
  for (int r = 0; r < 4; ++r) inv[r] = 1.f / l_r[r];
  ushort* orow = Oc + ((size_t)(b * Tseq + qt * 64 + w * 16)) * Cdim + h * HSd;
#pragma unroll
  for (int j = 0; j < 4; ++j)
#pragma unroll
    for (int r = 0; r < 4; ++r)
      orow[(size_t)(g * 4 + r) * Cdim + j * 16 + n16] = f2bf(oacc[j][r] * inv[r]);
}

// ---------------------------------------------------------------------------
extern "C" void kernel_launch(void* const* d_in, const int* in_sizes, int n_in,
                              void* d_out, int out_size, void* d_ws, size_t ws_size,
                              hipStream_t stream) {
  const float* x      = (const float*)d_in[0];
  const float* ln1_w  = (const float*)d_in[1];
  const float* ln1_b  = (const float*)d_in[2];
  const float* Wq     = (const float*)d_in[3];
  const float* bq     = (const float*)d_in[4];
  const float* Wk     = (const float*)d_in[5];
  const float* bk     = (const float*)d_in[6];
  const float* Wv     = (const float*)d_in[7];
  const float* bv     = (const float*)d_in[8];
  const float* Wproj  = (const float*)d_in[9];
  const float* bproj  = (const float*)d_in[10];
  const float* ln2_w  = (const float*)d_in[11];
  const float* ln2_b  = (const float*)d_in[12];
  const float* W1     = (const float*)d_in[13];
  const float* b1     = (const float*)d_in[14];
  const float* W2     = (const float*)d_in[15];
  const float* b2     = (const float*)d_in[16];
  float* out = (float*)d_out;

  // Workspace layout (~110 MB). QKV is one flat [M][1152] bf16 buffer;
  // x1 aliases it (QKV dead after attn; proj writes x1 afterwards).
  char* p = (char*)d_ws;
  ushort* h     = (ushort*)p;  p += (size_t)Mrows * Cdim * 2;   // reused as h2
  ushort* QKV   = (ushort*)p;  p += (size_t)Mrows * Nqkv * 2;   // x1 aliases
  ushort* Oc    = (ushort*)p;  p += (size_t)Mrows * Cdim * 2;
  ushort* g     = (ushort*)p;  p += (size_t)Mrows * Cffn * 2;
  ushort* WqkvT = (ushort*)p;  p += (size_t)Nqkv * Cdim * 2;
  ushort* WprojT= (ushort*)p;  p += (size_t)Cdim * Cdim * 2;
  ushort* W1T   = (ushort*)p;  p += (size_t)Cffn * Cdim * 2;
  ushort* W2T   = (ushort*)p;  p += (size_t)Cdim * Cffn * 2;
  float*  bqkv  = (float*)p;   p += (size_t)Nqkv * 4;
  ushort* h2 = h;
  ushort* x1 = QKV;

  dim3 blk(256), blk512(512);

  // 0. Fused weight prep + LN1 (one launch)
  prep_kernel<<<dim3(1733 + Mrows / 4), blk, 0, stream>>>(
      Wq, Wk, Wv, Wproj, W1, W2, bq, bk, bv, x, ln1_w, ln1_b,
      WqkvT, WprojT, W1T, W2T, bqkv, h);

  // 1. QKV fused GEMM -> flat [M][1152], per-head pih-permuted dims
  mfma_gemm<3, 128><<<dim3(Nqkv / 128, Mrows / 128), blk512, 0, stream>>>(
      h, WqkvT, bqkv, nullptr, QKV, nullptr, nullptr, Mrows, Nqkv, Cdim);

  // 2. MFMA flash attention -> Oc (bf16, concat layout)
  attn_kernel<<<dim3(Bsz * Hh, 4), blk, 0, stream>>>(QKV, Oc);

  // 3. x1 = x + Oc @ Wproj + bproj -> bf16 (skinny N: BN=64)
  mfma_gemm<1, 64><<<dim3(Cdim / 64, Mrows / 128), blk512, 0, stream>>>(
      Oc, WprojT, bproj, x, x1, nullptr, nullptr, Mrows, Cdim, Cdim);

  // 4. LN2 -> h2 (bf16, reads bf16 x1)
  ln_kernel<ushort><<<dim3(Mrows / 4), blk, 0, stream>>>(x1, ln2_w, ln2_b, h2, Mrows);

  // 5. g = gelu(h2 @ W1 + b1), per-64-block pih-permuted layout (bf16)
  mfma_gemm<2, 128><<<dim3(Cffn / 128, Mrows / 128), blk512, 0, stream>>>(
      h2, W1T, b1, nullptr, g, nullptr, nullptr, Mrows, Cffn, Cdim);

  // 6. out = x1 + g @ W2 + b2 -> fp32 (bf16 residual; W2T pih-matched)
  mfma_gemm<4, 64><<<dim3(Cdim / 64, Mrows / 128), blk512, 0, stream>>>(
      g, W2T, b2, x1, out, nullptr, nullptr, Mrows, Cdim, Cffn);
}